// Round 1
// baseline (147.256 us; speedup 1.0000x reference)
//
#include <hip/hip_runtime.h>

// Mamba selective scan: BATCH=2, DIM=768, L=2048, N=16, all fp32.
// Chunked 3-pass linear scan + B/C transpose. See journal for derivation.

#define LOG2E 1.4426950408889634f
#define LN2   0.6931471805599453f

constexpr int BATCH = 2, DIM = 768, L = 2048, N = 16;
constexpr int NC = 64, LC = 32;            // chunks per sequence, steps per chunk
static_assert(NC * LC == L, "chunking must cover L");

__device__ __forceinline__ float fexp2(float x) {
#if __has_builtin(__builtin_amdgcn_exp2f)
  return __builtin_amdgcn_exp2f(x);
#else
  return exp2f(x);
#endif
}

__device__ __forceinline__ float frcp(float x) {
#if __has_builtin(__builtin_amdgcn_rcpf)
  return __builtin_amdgcn_rcpf(x);
#else
  return 1.0f / x;
#endif
}

// softplus(v) = ln(1+e^v) = ln2 * log2(1 + 2^(v*log2e)); inputs here are ~[-1,2]
__device__ __forceinline__ float softplus(float v) {
  float s = LN2 * __log2f(1.0f + fexp2(v * LOG2E));
  return (v > 20.0f) ? v : s;
}

__device__ __forceinline__ float silu(float v) {
  float e = fexp2(-v * LOG2E);
  return v * frcp(1.0f + e);
}

// ---------------- pass 0: transpose B,C (b,n,l) -> (b,l,n) ----------------
__global__ __launch_bounds__(256) void k_transpose(
    const float* __restrict__ Bm, const float* __restrict__ Cm,
    float* __restrict__ Bt, float* __restrict__ Ct) {
  int g = blockIdx.x * 256 + threadIdx.x;    // over BATCH*L
  int l = g % L, b = g / L;
#pragma unroll
  for (int n = 0; n < N; n++) {
    Bt[((long)b * L + l) * N + n] = Bm[((long)b * N + n) * L + l];
    Ct[((long)b * L + l) * N + n] = Cm[((long)b * N + n) * L + l];
  }
}

// ---------------- pass 1: per-chunk local scan -> h (final state), P (decay) ----------------
__global__ __launch_bounds__(64) void k_pass1(
    const float* __restrict__ u, const float* __restrict__ delta,
    const float* __restrict__ A, const float* __restrict__ dbias,
    const float* __restrict__ Bt, float* __restrict__ h, float* __restrict__ P) {
  int bi = blockIdx.x;                 // NC*24 blocks: 24 consecutive blocks share a chunk c
  int c = bi / 24;
  int r = bi % 24;
  int b = r / 12;
  int dg = r % 12;
  int d = dg * 64 + threadIdx.x;

  float A2[N];
#pragma unroll
  for (int n = 0; n < N; n++) A2[n] = A[d * N + n] * LOG2E;
  float bias = dbias[d];

  float x[N];
#pragma unroll
  for (int n = 0; n < N; n++) x[n] = 0.0f;
  float S = 0.0f;

  long base = ((long)(b * DIM + d)) * L + c * LC;
  const float* Brow = Bt + ((long)b * L + c * LC) * N;   // wave-uniform

  for (int half = 0; half < 2; ++half) {
    float dl[16], uu[16];
#pragma unroll
    for (int j4 = 0; j4 < 4; j4++) {
      float4 dv = *(const float4*)(delta + base + half * 16 + j4 * 4);
      float4 uv = *(const float4*)(u + base + half * 16 + j4 * 4);
      dl[j4 * 4 + 0] = dv.x; dl[j4 * 4 + 1] = dv.y; dl[j4 * 4 + 2] = dv.z; dl[j4 * 4 + 3] = dv.w;
      uu[j4 * 4 + 0] = uv.x; uu[j4 * 4 + 1] = uv.y; uu[j4 * 4 + 2] = uv.z; uu[j4 * 4 + 3] = uv.w;
    }
#pragma unroll
    for (int j = 0; j < 16; j++) {
      float sp = softplus(dl[j] + bias);
      S += sp;
      float du = sp * uu[j];
      const float* br = Brow + (half * 16 + j) * N;      // wave-uniform row
#pragma unroll
      for (int n = 0; n < N; n++) {
        float a = fexp2(sp * A2[n]);
        x[n] = a * x[n] + du * br[n];
      }
    }
  }

  long hb = ((long)(b * DIM + d) * NC + c) * N;
#pragma unroll
  for (int n = 0; n < N; n++) {
    h[hb + n] = x[n];
    P[hb + n] = fexp2(S * A2[n]);   // prod over chunk of exp(dl*A) = exp(A*sum dl)
  }
}

// ---------------- pass 2: sequential combine over chunks; h <- x_init(chunk) in place ----------------
__global__ __launch_bounds__(256) void k_pass2(float* __restrict__ h, const float* __restrict__ P) {
  int t = blockIdx.x * 256 + threadIdx.x;   // over BATCH*DIM*N
  int n = t % N;
  int bd = t / N;
  long base = (long)bd * NC * N + n;
  float x = 0.0f;
#pragma unroll 8
  for (int c = 0; c < NC; c++) {
    long i = base + (long)c * N;
    float Pc = P[i];
    float hc = h[i];
    h[i] = x;               // x_init for chunk c
    x = Pc * x + hc;        // state at end of chunk c
  }
}

// ---------------- pass 3: full scan with correct init, produce output ----------------
__global__ __launch_bounds__(64) void k_pass3(
    const float* __restrict__ u, const float* __restrict__ delta,
    const float* __restrict__ A, const float* __restrict__ dbias,
    const float* __restrict__ Bt, const float* __restrict__ Ct,
    const float* __restrict__ Dv, const float* __restrict__ z,
    const float* __restrict__ xinit, float* __restrict__ out) {
  int bi = blockIdx.x;
  int c = bi / 24;
  int r = bi % 24;
  int b = r / 12;
  int dg = r % 12;
  int d = dg * 64 + threadIdx.x;

  float A2[N];
#pragma unroll
  for (int n = 0; n < N; n++) A2[n] = A[d * N + n] * LOG2E;
  float bias = dbias[d];
  float Dd = Dv[d];

  long hb = ((long)(b * DIM + d) * NC + c) * N;
  float x[N];
#pragma unroll
  for (int n = 0; n < N; n++) x[n] = xinit[hb + n];

  long base = ((long)(b * DIM + d)) * L + c * LC;
  const float* Brow = Bt + ((long)b * L + c * LC) * N;
  const float* Crow = Ct + ((long)b * L + c * LC) * N;

  for (int half = 0; half < 2; ++half) {
    float dl[16], uu[16], y[16];
#pragma unroll
    for (int j4 = 0; j4 < 4; j4++) {
      float4 dv = *(const float4*)(delta + base + half * 16 + j4 * 4);
      float4 uv = *(const float4*)(u + base + half * 16 + j4 * 4);
      dl[j4 * 4 + 0] = dv.x; dl[j4 * 4 + 1] = dv.y; dl[j4 * 4 + 2] = dv.z; dl[j4 * 4 + 3] = dv.w;
      uu[j4 * 4 + 0] = uv.x; uu[j4 * 4 + 1] = uv.y; uu[j4 * 4 + 2] = uv.z; uu[j4 * 4 + 3] = uv.w;
    }
#pragma unroll
    for (int j = 0; j < 16; j++) {
      float sp = softplus(dl[j] + bias);
      float du = sp * uu[j];
      const float* br = Brow + (half * 16 + j) * N;
      const float* cr = Crow + (half * 16 + j) * N;
      float acc = 0.0f;
#pragma unroll
      for (int n = 0; n < N; n++) {
        float a = fexp2(sp * A2[n]);
        x[n] = a * x[n] + du * br[n];
        acc += x[n] * cr[n];
      }
      y[j] = acc;
    }
    // epilogue for these 16 steps: out = (y + u*D) * silu(z)
#pragma unroll
    for (int j4 = 0; j4 < 4; j4++) {
      float4 zv = *(const float4*)(z + base + half * 16 + j4 * 4);
      float4 ov;
      ov.x = (y[j4 * 4 + 0] + uu[j4 * 4 + 0] * Dd) * silu(zv.x);
      ov.y = (y[j4 * 4 + 1] + uu[j4 * 4 + 1] * Dd) * silu(zv.y);
      ov.z = (y[j4 * 4 + 2] + uu[j4 * 4 + 2] * Dd) * silu(zv.z);
      ov.w = (y[j4 * 4 + 3] + uu[j4 * 4 + 3] * Dd) * silu(zv.w);
      *(float4*)(out + base + half * 16 + j4 * 4) = ov;
    }
  }
}

// ---------------- fallback (ws too small): n-parallel single pass ----------------
__global__ __launch_bounds__(256) void k_simple(
    const float* __restrict__ u, const float* __restrict__ delta,
    const float* __restrict__ A, const float* __restrict__ dbias,
    const float* __restrict__ Bm, const float* __restrict__ Cm,
    const float* __restrict__ Dv, const float* __restrict__ z,
    float* __restrict__ out) {
  int t = blockIdx.x * 256 + threadIdx.x;   // BATCH*DIM*N threads
  int n = t % N;
  int bd = t / N;
  int d = bd % DIM;
  int b = bd / DIM;
  float A2 = A[d * N + n] * LOG2E;
  float bias = dbias[d];
  float Dd = Dv[d];
  const float* Bp = Bm + ((long)b * N + n) * L;
  const float* Cp = Cm + ((long)b * N + n) * L;
  long base = (long)bd * L;
  float x = 0.0f;
  for (int l = 0; l < L; l++) {
    float dv = delta[base + l];
    float uv = u[base + l];
    float sp = softplus(dv + bias);
    float a = fexp2(sp * A2);
    x = a * x + sp * uv * Bp[l];
    float y = x * Cp[l];
#pragma unroll
    for (int off = 8; off; off >>= 1) y += __shfl_xor(y, off, 16);
    if (n == 0) {
      float zv = z[base + l];
      out[base + l] = (y + uv * Dd) * silu(zv);
    }
  }
}

extern "C" void kernel_launch(void* const* d_in, const int* in_sizes, int n_in,
                              void* d_out, int out_size, void* d_ws, size_t ws_size,
                              hipStream_t stream) {
  const float* u     = (const float*)d_in[0];
  const float* delta = (const float*)d_in[1];
  const float* A     = (const float*)d_in[2];
  const float* Bm    = (const float*)d_in[3];
  const float* Cm    = (const float*)d_in[4];
  const float* Dv    = (const float*)d_in[5];
  const float* z     = (const float*)d_in[6];
  const float* dbias = (const float*)d_in[7];
  float* out = (float*)d_out;

  const size_t btct = (size_t)BATCH * L * N;            // 65536 floats each
  const size_t hp   = (size_t)BATCH * DIM * NC * N;     // 1572864 floats each
  const size_t need = (2 * btct + 2 * hp) * sizeof(float);

  if (ws_size < need) {
    // insurance path: single-kernel n-parallel scan, no workspace
    k_simple<<<(BATCH * DIM * N) / 256, 256, 0, stream>>>(u, delta, A, dbias, Bm, Cm, Dv, z, out);
    return;
  }

  float* ws = (float*)d_ws;
  float* Bt = ws;
  float* Ct = Bt + btct;
  float* h  = Ct + btct;
  float* P  = h + hp;

  k_transpose<<<(BATCH * L) / 256, 256, 0, stream>>>(Bm, Cm, Bt, Ct);
  k_pass1<<<NC * 24, 64, 0, stream>>>(u, delta, A, dbias, Bt, h, P);
  k_pass2<<<(BATCH * DIM * N) / 256, 256, 0, stream>>>(h, P);
  k_pass3<<<NC * 24, 64, 0, stream>>>(u, delta, A, dbias, Bt, Ct, Dv, z, h, out);
}

// Round 2
// 140.870 us; speedup vs baseline: 1.0453x; 1.0453x over previous
//
#include <hip/hip_runtime.h>

// Mamba selective scan: BATCH=2, DIM=768, L=2048, N=16, fp32.
// R2: 3-pass chunked scan, NC=128 chunks of LC=16, B/C staged in LDS per block
// (no separate transpose kernel), h laid out [b][c][d][n] for coalescing,
// per-chunk decay stored as scalar S = sum(softplus) and recomputed in pass2.

#define LOG2E 1.4426950408889634f
#define LN2   0.6931471805599453f

constexpr int BATCH = 2, DIM = 768, L = 2048, N = 16;
constexpr int NC = 128, LC = 16;      // chunks per sequence, steps per chunk
constexpr int DG = DIM / 64;          // 12 d-groups of 64 lanes
constexpr int CPB = 4;                // chunks per block (1 per wave)
constexpr int CG = NC / CPB;          // 32 chunk-groups
static_assert(NC * LC == L, "chunking must cover L");

__device__ __forceinline__ float fexp2(float x) { return __builtin_amdgcn_exp2f(x); }

// softplus(v) = ln(1+e^v); inputs ~[-1,2], guard large v
__device__ __forceinline__ float softplus(float v) {
  float s = LN2 * __log2f(1.0f + fexp2(v * LOG2E));
  return (v > 20.0f) ? v : s;
}

__device__ __forceinline__ float silu(float v) {
  return v / (1.0f + fexp2(-v * LOG2E));
}

// ---------------- pass 1: per-chunk local scan -> h (chunk-final state), S (sum softplus) ----------------
__global__ __launch_bounds__(256) void k_pass1(
    const float* __restrict__ u, const float* __restrict__ delta,
    const float* __restrict__ A, const float* __restrict__ dbias,
    const float* __restrict__ Bg, float* __restrict__ h, float* __restrict__ Ssum) {
  __shared__ float Bs[N][CPB * LC + 4];   // 16 x 68 (pad kills write conflicts)
  int blk = blockIdx.x;                   // (b, dg, cg)
  int cg = blk % CG;
  int r = blk / CG;
  int dg = r % DG;
  int b = r / DG;
  int t = threadIdx.x;

  {  // stage B chunk-group slab: rows n, 64 consecutive l
    int n = t >> 4, jj = t & 15;
    const float* src = Bg + ((long)(b * N + n)) * L + cg * (CPB * LC) + jj * 4;
    float4 v = *(const float4*)src;
    Bs[n][jj * 4 + 0] = v.x; Bs[n][jj * 4 + 1] = v.y;
    Bs[n][jj * 4 + 2] = v.z; Bs[n][jj * 4 + 3] = v.w;
  }

  int wave = t >> 6, lane = t & 63;
  int c = cg * CPB + wave;
  int d = dg * 64 + lane;

  float A2[N];
#pragma unroll
  for (int q = 0; q < 4; q++) {
    float4 av = *(const float4*)(A + d * N + q * 4);
    A2[q * 4 + 0] = av.x * LOG2E; A2[q * 4 + 1] = av.y * LOG2E;
    A2[q * 4 + 2] = av.z * LOG2E; A2[q * 4 + 3] = av.w * LOG2E;
  }
  float bias = dbias[d];

  long base = ((long)(b * DIM + d)) * L + c * LC;
  float dl[LC], uu[LC];
#pragma unroll
  for (int j4 = 0; j4 < 4; j4++) {
    float4 dv = *(const float4*)(delta + base + j4 * 4);
    float4 uv = *(const float4*)(u + base + j4 * 4);
    dl[j4 * 4 + 0] = dv.x; dl[j4 * 4 + 1] = dv.y; dl[j4 * 4 + 2] = dv.z; dl[j4 * 4 + 3] = dv.w;
    uu[j4 * 4 + 0] = uv.x; uu[j4 * 4 + 1] = uv.y; uu[j4 * 4 + 2] = uv.z; uu[j4 * 4 + 3] = uv.w;
  }

  float sp[LC], S = 0.0f;
#pragma unroll
  for (int j = 0; j < LC; j++) { sp[j] = softplus(dl[j] + bias); S += sp[j]; }

  __syncthreads();   // Bs ready

  float x[N];
#pragma unroll
  for (int n = 0; n < N; n++) x[n] = 0.0f;
  int col0 = wave * LC;
#pragma unroll
  for (int j = 0; j < LC; j++) {
    float du = sp[j] * uu[j];
#pragma unroll
    for (int n = 0; n < N; n++) {
      float a = fexp2(sp[j] * A2[n]);
      x[n] = a * x[n] + du * Bs[n][col0 + j];
    }
  }

  long hb = ((long)((b * NC + c) * DIM + d)) * N;   // [b][c][d][n] -> coalesced
#pragma unroll
  for (int q = 0; q < 4; q++) {
    float4 v; v.x = x[q * 4 + 0]; v.y = x[q * 4 + 1]; v.z = x[q * 4 + 2]; v.w = x[q * 4 + 3];
    *(float4*)(h + hb + q * 4) = v;
  }
  Ssum[(b * NC + c) * DIM + d] = S;
}

// ---------------- pass 2: serial combine over chunks; h <- x_init(chunk) in place ----------------
__global__ __launch_bounds__(256) void k_pass2(
    float* __restrict__ h, const float* __restrict__ Ssum, const float* __restrict__ A) {
  int g = blockIdx.x * 256 + threadIdx.x;   // over BATCH*DIM*N
  int n = g & 15;
  int d = (g >> 4) % DIM;
  int b = g / (16 * DIM);
  float A2 = A[d * N + n] * LOG2E;
  float x = 0.0f;
#pragma unroll 4
  for (int c = 0; c < NC; c++) {
    long idx = ((long)((b * NC + c) * DIM + d)) * N + n;
    float hc = h[idx];
    float Sc = Ssum[(b * NC + c) * DIM + d];
    float xi = x;
    x = fexp2(Sc * A2) * x + hc;
    h[idx] = xi;                 // x_init for chunk c (coalesced)
  }
}

// ---------------- pass 3: full scan with correct init, produce output ----------------
__global__ __launch_bounds__(256) void k_pass3(
    const float* __restrict__ u, const float* __restrict__ delta,
    const float* __restrict__ A, const float* __restrict__ dbias,
    const float* __restrict__ Bg, const float* __restrict__ Cg,
    const float* __restrict__ Dv, const float* __restrict__ z,
    const float* __restrict__ xinit, float* __restrict__ out) {
  __shared__ float Bs[N][CPB * LC + 4];
  __shared__ float Cs[N][CPB * LC + 4];
  int blk = blockIdx.x;
  int cg = blk % CG;
  int r = blk / CG;
  int dg = r % DG;
  int b = r / DG;
  int t = threadIdx.x;

  {
    int n = t >> 4, jj = t & 15;
    long off = ((long)(b * N + n)) * L + cg * (CPB * LC) + jj * 4;
    float4 v = *(const float4*)(Bg + off);
    Bs[n][jj * 4 + 0] = v.x; Bs[n][jj * 4 + 1] = v.y;
    Bs[n][jj * 4 + 2] = v.z; Bs[n][jj * 4 + 3] = v.w;
    float4 w = *(const float4*)(Cg + off);
    Cs[n][jj * 4 + 0] = w.x; Cs[n][jj * 4 + 1] = w.y;
    Cs[n][jj * 4 + 2] = w.z; Cs[n][jj * 4 + 3] = w.w;
  }

  int wave = t >> 6, lane = t & 63;
  int c = cg * CPB + wave;
  int d = dg * 64 + lane;

  float A2[N];
#pragma unroll
  for (int q = 0; q < 4; q++) {
    float4 av = *(const float4*)(A + d * N + q * 4);
    A2[q * 4 + 0] = av.x * LOG2E; A2[q * 4 + 1] = av.y * LOG2E;
    A2[q * 4 + 2] = av.z * LOG2E; A2[q * 4 + 3] = av.w * LOG2E;
  }
  float bias = dbias[d];
  float Dd = Dv[d];

  long hb = ((long)((b * NC + c) * DIM + d)) * N;
  float x[N];
#pragma unroll
  for (int q = 0; q < 4; q++) {
    float4 v = *(const float4*)(xinit + hb + q * 4);
    x[q * 4 + 0] = v.x; x[q * 4 + 1] = v.y; x[q * 4 + 2] = v.z; x[q * 4 + 3] = v.w;
  }

  long base = ((long)(b * DIM + d)) * L + c * LC;
  float dl[LC], uu[LC];
#pragma unroll
  for (int j4 = 0; j4 < 4; j4++) {
    float4 dv = *(const float4*)(delta + base + j4 * 4);
    float4 uv = *(const float4*)(u + base + j4 * 4);
    dl[j4 * 4 + 0] = dv.x; dl[j4 * 4 + 1] = dv.y; dl[j4 * 4 + 2] = dv.z; dl[j4 * 4 + 3] = dv.w;
    uu[j4 * 4 + 0] = uv.x; uu[j4 * 4 + 1] = uv.y; uu[j4 * 4 + 2] = uv.z; uu[j4 * 4 + 3] = uv.w;
  }

  float sp[LC];
#pragma unroll
  for (int j = 0; j < LC; j++) sp[j] = softplus(dl[j] + bias);

  __syncthreads();

  float y[LC];
  int col0 = wave * LC;
#pragma unroll
  for (int j = 0; j < LC; j++) {
    float du = sp[j] * uu[j];
    float acc = 0.0f;
#pragma unroll
    for (int n = 0; n < N; n++) {
      float a = fexp2(sp[j] * A2[n]);
      x[n] = a * x[n] + du * Bs[n][col0 + j];
      acc += x[n] * Cs[n][col0 + j];
    }
    y[j] = acc;
  }

#pragma unroll
  for (int j4 = 0; j4 < 4; j4++) {
    float4 zv = *(const float4*)(z + base + j4 * 4);
    float4 ov;
    ov.x = (y[j4 * 4 + 0] + uu[j4 * 4 + 0] * Dd) * silu(zv.x);
    ov.y = (y[j4 * 4 + 1] + uu[j4 * 4 + 1] * Dd) * silu(zv.y);
    ov.z = (y[j4 * 4 + 2] + uu[j4 * 4 + 2] * Dd) * silu(zv.z);
    ov.w = (y[j4 * 4 + 3] + uu[j4 * 4 + 3] * Dd) * silu(zv.w);
    *(float4*)(out + base + j4 * 4) = ov;
  }
}

// ---------------- fallback (ws too small): n-parallel single pass ----------------
__global__ __launch_bounds__(256) void k_simple(
    const float* __restrict__ u, const float* __restrict__ delta,
    const float* __restrict__ A, const float* __restrict__ dbias,
    const float* __restrict__ Bm, const float* __restrict__ Cm,
    const float* __restrict__ Dv, const float* __restrict__ z,
    float* __restrict__ out) {
  int t = blockIdx.x * 256 + threadIdx.x;
  int n = t % N;
  int bd = t / N;
  int d = bd % DIM;
  int b = bd / DIM;
  float A2 = A[d * N + n] * LOG2E;
  float bias = dbias[d];
  float Dd = Dv[d];
  const float* Bp = Bm + ((long)b * N + n) * L;
  const float* Cp = Cm + ((long)b * N + n) * L;
  long base = (long)bd * L;
  float x = 0.0f;
  for (int l = 0; l < L; l++) {
    float dv = delta[base + l];
    float uv = u[base + l];
    float sp = softplus(dv + bias);
    float a = fexp2(sp * A2);
    x = a * x + sp * uv * Bp[l];
    float y = x * Cp[l];
#pragma unroll
    for (int off = 8; off; off >>= 1) y += __shfl_xor(y, off, 16);
    if (n == 0) {
      float zv = z[base + l];
      out[base + l] = (y + uv * Dd) * silu(zv);
    }
  }
}

extern "C" void kernel_launch(void* const* d_in, const int* in_sizes, int n_in,
                              void* d_out, int out_size, void* d_ws, size_t ws_size,
                              hipStream_t stream) {
  const float* u     = (const float*)d_in[0];
  const float* delta = (const float*)d_in[1];
  const float* A     = (const float*)d_in[2];
  const float* Bm    = (const float*)d_in[3];
  const float* Cm    = (const float*)d_in[4];
  const float* Dv    = (const float*)d_in[5];
  const float* z     = (const float*)d_in[6];
  const float* dbias = (const float*)d_in[7];
  float* out = (float*)d_out;

  const size_t hp = (size_t)BATCH * NC * DIM * N;   // 3.15M floats
  const size_t sp = (size_t)BATCH * NC * DIM;       // 196K floats
  const size_t need = (hp + sp) * sizeof(float);

  if (ws_size < need) {
    k_simple<<<(BATCH * DIM * N) / 256, 256, 0, stream>>>(u, delta, A, dbias, Bm, Cm, Dv, z, out);
    return;
  }

  float* h = (float*)d_ws;
  float* S = h + hp;

  const int grid13 = BATCH * DG * CG;   // 768 blocks x 256 threads
  k_pass1<<<grid13, 256, 0, stream>>>(u, delta, A, dbias, Bm, h, S);
  k_pass2<<<(BATCH * DIM * N) / 256, 256, 0, stream>>>(h, S, A);
  k_pass3<<<grid13, 256, 0, stream>>>(u, delta, A, dbias, Bm, Cm, Dv, z, h, out);
}

// Round 5
// 130.720 us; speedup vs baseline: 1.1265x; 1.0776x over previous
//
#include <hip/hip_runtime.h>

// Mamba selective scan: BATCH=2, DIM=768, L=2048, N=16, fp32.
// R5: 3 plain kernels (cooperative launch failed silently in R4).
//  pass1: stage delta/u coalesced into LDS [64d][64l] (+B [16n][64l]);
//         per-wave chunk scan (LC=16); h stored [b][c][n][d] coalesced.
//  pass2: cross-chunk combine, d-fastest thread map, h -> x_init in place.
//  pass3: restage + rescan with inits; y via LDS slab; coalesced epilogue.

#define LOG2E 1.4426950408889634f
#define LN2   0.6931471805599453f

constexpr int BATCH = 2, DIM = 768, L = 2048, N = 16;
constexpr int NC = 128, LC = 16;       // chunks, steps per chunk
constexpr int DG = DIM / 64;           // 12 d-groups
constexpr int CPB = 4;                 // chunks per block (1 per wave)
constexpr int CG = NC / CPB;           // 32 chunk-groups
constexpr int NBLK = BATCH * DG * CG;  // 768 blocks
constexpr int NCOMB = BATCH * DIM * N; // 24576 combine threads
static_assert(NC * LC == L, "chunking must cover L");

__device__ __forceinline__ float fexp2(float x) { return __builtin_amdgcn_exp2f(x); }
__device__ __forceinline__ float softplus(float v) {
  float s = LN2 * __log2f(1.0f + fexp2(v * LOG2E));
  return (v > 20.0f) ? v : s;
}
__device__ __forceinline__ float silu(float v) { return v / (1.0f + fexp2(-v * LOG2E)); }

// ---------------- pass 1 ----------------
__global__ __launch_bounds__(256, 4) void k_pass1(
    const float* __restrict__ u, const float* __restrict__ delta,
    const float* __restrict__ A, const float* __restrict__ dbias,
    const float* __restrict__ Bg, float* __restrict__ h, float* __restrict__ S)
{
  __shared__ float ds_[64][65];
  __shared__ float us[64][65];
  __shared__ float Bs[N][65];

  const int bid = blockIdx.x, t = threadIdx.x;
  const int cgi = bid & 31;
  const int dgb = bid >> 5;
  const int dg = dgb % DG;
  const int b = dgb / DG;
  const int d0 = dg * 64, l0 = cgi * 64;

  {  // coalesced staging
    const int row16 = t >> 4;
    const int col4 = (t & 15) * 4;
#pragma unroll
    for (int rr = 0; rr < 4; rr++) {
      int row = row16 + rr * 16;
      long gof = ((long)(b * DIM + d0 + row)) * L + l0 + col4;
      *(float4*)&ds_[row][col4] = *(const float4*)(delta + gof);
      *(float4*)&us[row][col4]  = *(const float4*)(u + gof);
    }
    long bof = ((long)(b * N + row16)) * L + l0 + col4;
    *(float4*)&Bs[row16][col4] = *(const float4*)(Bg + bof);
  }

  const int w = t >> 6, lane = t & 63;
  const int c = cgi * CPB + w;
  const int d = d0 + lane;

  float A2[N];
#pragma unroll
  for (int q = 0; q < 4; q++) {
    float4 av = *(const float4*)(A + d * N + q * 4);
    A2[q*4+0] = av.x * LOG2E; A2[q*4+1] = av.y * LOG2E;
    A2[q*4+2] = av.z * LOG2E; A2[q*4+3] = av.w * LOG2E;
  }
  const float bias = dbias[d];

  __syncthreads();

  float sp[LC], uu[LC], Ssum = 0.f;
#pragma unroll
  for (int j = 0; j < LC; j++) {
    float dv = ds_[lane][w * LC + j];
    uu[j] = us[lane][w * LC + j];
    sp[j] = softplus(dv + bias);
    Ssum += sp[j];
  }

  float x[N];
#pragma unroll
  for (int n = 0; n < N; n++) x[n] = 0.f;
#pragma unroll
  for (int j = 0; j < LC; j++) {
    float du = sp[j] * uu[j];
#pragma unroll
    for (int n = 0; n < N; n++) {
      float a = fexp2(sp[j] * A2[n]);
      x[n] = a * x[n] + du * Bs[n][w * LC + j];
    }
  }

  // h layout [b][c][n][d] -> 16 coalesced b32 stores
  const long hb = ((long)(b * NC + c)) * N * DIM + d;
#pragma unroll
  for (int n = 0; n < N; n++) h[hb + (long)n * DIM] = x[n];
  S[(b * NC + c) * DIM + d] = Ssum;
}

// ---------------- pass 2: combine (d-fastest map) ----------------
__global__ __launch_bounds__(256) void k_pass2(
    float* __restrict__ h, const float* __restrict__ S, const float* __restrict__ A)
{
  int g = blockIdx.x * 256 + threadIdx.x;   // g = (bb*16 + n)*768 + dd
  int dd = g % DIM;
  int r = g / DIM;
  int n = r & 15;
  int bb = r >> 4;
  float a2 = A[dd * N + n] * LOG2E;
  float x = 0.f;
#pragma unroll 8
  for (int cc = 0; cc < NC; cc++) {
    long idx = (((long)(bb * NC + cc)) * N + n) * DIM + dd;
    float hc = h[idx];
    float Sc = S[(bb * NC + cc) * DIM + dd];
    h[idx] = x;                     // x_init for chunk cc
    x = fexp2(Sc * a2) * x + hc;
  }
}

// ---------------- pass 3 ----------------
__global__ __launch_bounds__(256, 3) void k_pass3(
    const float* __restrict__ u, const float* __restrict__ delta,
    const float* __restrict__ A, const float* __restrict__ dbias,
    const float* __restrict__ Bg, const float* __restrict__ Cg,
    const float* __restrict__ Dv, const float* __restrict__ z,
    const float* __restrict__ xinit, float* __restrict__ out)
{
  __shared__ float ds_[64][65];   // delta slab, reused as y slab
  __shared__ float us[64][65];
  __shared__ float Bs[N][65];
  __shared__ float Cs[N][65];

  const int bid = blockIdx.x, t = threadIdx.x;
  const int cgi = bid & 31;
  const int dgb = bid >> 5;
  const int dg = dgb % DG;
  const int b = dgb / DG;
  const int d0 = dg * 64, l0 = cgi * 64;

  {
    const int row16 = t >> 4;
    const int col4 = (t & 15) * 4;
#pragma unroll
    for (int rr = 0; rr < 4; rr++) {
      int row = row16 + rr * 16;
      long gof = ((long)(b * DIM + d0 + row)) * L + l0 + col4;
      *(float4*)&ds_[row][col4] = *(const float4*)(delta + gof);
      *(float4*)&us[row][col4]  = *(const float4*)(u + gof);
    }
    long bof = ((long)(b * N + row16)) * L + l0 + col4;
    *(float4*)&Bs[row16][col4] = *(const float4*)(Bg + bof);
    *(float4*)&Cs[row16][col4] = *(const float4*)(Cg + bof);
  }

  const int w = t >> 6, lane = t & 63;
  const int c = cgi * CPB + w;
  const int d = d0 + lane;

  float A2[N];
#pragma unroll
  for (int q = 0; q < 4; q++) {
    float4 av = *(const float4*)(A + d * N + q * 4);
    A2[q*4+0] = av.x * LOG2E; A2[q*4+1] = av.y * LOG2E;
    A2[q*4+2] = av.z * LOG2E; A2[q*4+3] = av.w * LOG2E;
  }
  const float bias = dbias[d];

  // x_init: [b][c][n][d] -> 16 coalesced b32 loads
  const long hb = ((long)(b * NC + c)) * N * DIM + d;
  float x[N];
#pragma unroll
  for (int n = 0; n < N; n++) x[n] = xinit[hb + (long)n * DIM];

  __syncthreads();

  float sp[LC], uu[LC];
#pragma unroll
  for (int j = 0; j < LC; j++) {
    float dv = ds_[lane][w * LC + j];
    uu[j] = us[lane][w * LC + j];
    sp[j] = softplus(dv + bias);
  }

  __syncthreads();   // done reading ds_ as delta; will rewrite as y

  float y[LC];
#pragma unroll
  for (int j = 0; j < LC; j++) {
    float du = sp[j] * uu[j];
    float acc = 0.f;
#pragma unroll
    for (int n = 0; n < N; n++) {
      float a = fexp2(sp[j] * A2[n]);
      x[n] = a * x[n] + du * Bs[n][w * LC + j];
      acc += x[n] * Cs[n][w * LC + j];
    }
    y[j] = acc;
  }
#pragma unroll
  for (int j = 0; j < LC; j++) ds_[lane][w * LC + j] = y[j];

  __syncthreads();

  // coalesced fused epilogue: out = (y + u*D) * silu(z)
  {
    const int row16 = t >> 4;
    const int col4 = (t & 15) * 4;
#pragma unroll
    for (int rr = 0; rr < 4; rr++) {
      int row = row16 + rr * 16;
      long gof = ((long)(b * DIM + d0 + row)) * L + l0 + col4;
      float4 zv = *(const float4*)(z + gof);
      float4 yv = *(const float4*)&ds_[row][col4];
      float4 uv = *(const float4*)&us[row][col4];
      float Dd = Dv[d0 + row];
      float4 ov;
      ov.x = (yv.x + uv.x * Dd) * silu(zv.x);
      ov.y = (yv.y + uv.y * Dd) * silu(zv.y);
      ov.z = (yv.z + uv.z * Dd) * silu(zv.z);
      ov.w = (yv.w + uv.w * Dd) * silu(zv.w);
      *(float4*)(out + gof) = ov;
    }
  }
}

// ---------------- fallback (ws too small) ----------------
__global__ __launch_bounds__(256) void k_simple(
    const float* __restrict__ u, const float* __restrict__ delta,
    const float* __restrict__ A, const float* __restrict__ dbias,
    const float* __restrict__ Bm, const float* __restrict__ Cm,
    const float* __restrict__ Dv, const float* __restrict__ z,
    float* __restrict__ out) {
  int t = blockIdx.x * 256 + threadIdx.x;
  int n = t % N;
  int bd = t / N;
  int d = bd % DIM;
  int b = bd / DIM;
  float A2 = A[d * N + n] * LOG2E;
  float bias = dbias[d];
  float Dd = Dv[d];
  const float* Bp = Bm + ((long)b * N + n) * L;
  const float* Cp = Cm + ((long)b * N + n) * L;
  long base = (long)bd * L;
  float x = 0.0f;
  for (int l = 0; l < L; l++) {
    float dv = delta[base + l];
    float uv = u[base + l];
    float sp = softplus(dv + bias);
    float a = fexp2(sp * A2);
    x = a * x + sp * uv * Bp[l];
    float y = x * Cp[l];
#pragma unroll
    for (int off = 8; off; off >>= 1) y += __shfl_xor(y, off, 16);
    if (n == 0) {
      float zv = z[base + l];
      out[base + l] = (y + uv * Dd) * silu(zv);
    }
  }
}

extern "C" void kernel_launch(void* const* d_in, const int* in_sizes, int n_in,
                              void* d_out, int out_size, void* d_ws, size_t ws_size,
                              hipStream_t stream) {
  const float* u     = (const float*)d_in[0];
  const float* delta = (const float*)d_in[1];
  const float* A     = (const float*)d_in[2];
  const float* Bm    = (const float*)d_in[3];
  const float* Cm    = (const float*)d_in[4];
  const float* Dv    = (const float*)d_in[5];
  const float* z     = (const float*)d_in[6];
  const float* dbias = (const float*)d_in[7];
  float* out = (float*)d_out;

  const size_t hp = (size_t)BATCH * NC * DIM * N;   // 3.15M floats
  const size_t spn = (size_t)BATCH * NC * DIM;      // 196K floats
  const size_t need = (hp + spn) * sizeof(float);

  if (ws_size < need) {
    k_simple<<<(BATCH * DIM * N) / 256, 256, 0, stream>>>(u, delta, A, dbias, Bm, Cm, Dv, z, out);
    return;
  }

  float* h = (float*)d_ws;
  float* S = h + hp;

  k_pass1<<<NBLK, 256, 0, stream>>>(u, delta, A, dbias, Bm, h, S);
  k_pass2<<<NCOMB / 256, 256, 0, stream>>>(h, S, A);
  k_pass3<<<NBLK, 256, 0, stream>>>(u, delta, A, dbias, Bm, Cm, Dv, z, h, out);
}